// Round 7
// baseline (374.949 us; speedup 1.0000x reference)
//
#include <hip/hip_runtime.h>
#include <math.h>

// CapsuleLayer routing on MI355X (gfx950). fp32 in/out.
// B=64, n=2048, k=32, in_C=16, out_C=32, 3 routing iterations.
//
// Round-17: keep the verified round-13/16 structure (PNB=16, 1 block/CU,
// private partials, no atomics). Two quantified fixes:
//  1. reduce_squash3 was CU-count-bound: 64 blocks x 512KB stream at the
//     ~25GB/s/CU cap = 21us each. Split: stage-A (NK,2,4)=256 blocks sums
//     32 partials each (~6us), writes float4-packed vpart4[k][o][b][4];
//     the 4-chunk sum + squash folds in-register into the next pass's
//     orp build (round-14/15 verified math, one coalesced float4 per
//     (r,k)); tiny reduce_final makes the output. Saves ~35us net.
//  2. Depth-2 wq prefetch (VGPR headroom to 128 at 16 waves/block).
//     If pass dur is unchanged -> latency theory falsified.
// Grid back to (NSETS,2) -- round-6 proved the XCD swizzle neutral.

#define BATCH 64
#define NN    2048
#define NK    32
#define NI    16
#define NO    32

#define PNB   16                  // nodes per fused block
#define NSETS (NN / PNB)          // 128 node-sets
#define NCH   4                   // reduce stage-A chunks
#define XT_JS 528                 // ushorts per node-row in xt_lds (32*16 + 16 pad)

typedef __bf16 bf16x8 __attribute__((ext_vector_type(8)));
typedef float  f32x16 __attribute__((ext_vector_type(16)));

__device__ __forceinline__ unsigned short f2bf(float f) {
    unsigned int x = __float_as_uint(f);
    unsigned int lsb = (x >> 16) & 1u;
    x += 0x7fffu + lsb;                 // RNE
    return (unsigned short)(x >> 16);
}
__device__ __forceinline__ float bflo(unsigned int u) { return __uint_as_float(u << 16); }
__device__ __forceinline__ float bfhi(unsigned int u) { return __uint_as_float(u & 0xffff0000u); }

// W fp32 [n][k][i][o] -> wq bf16 [n][k][o][i] (A-fragment-ready).
__global__ __launch_bounds__(256) void wqt_kernel(const float* __restrict__ Wg,
                                                  unsigned short* __restrict__ wq) {
    const int w    = threadIdx.x >> 6;
    const int lane = threadIdx.x & 63;
    const int task = blockIdx.x * 4 + w;          // 65536 = n*32 + k
    const int o  = lane & 31;
    const int ih = lane >> 5;                     // i-half
    const float* src = Wg + (size_t)task * (NI * NO);
    unsigned short d[8];
#pragma unroll
    for (int j = 0; j < 8; ++j)
        d[j] = f2bf(src[(ih * 8 + j) * NO + o]);
    *(uint4*)(wq + (size_t)task * (NO * NI) + o * NI + ih * 8) = *(uint4*)d;
}

// ---------------- fused routing pass ----------------
// Grid (128 sets, 2 b-halves), block 1024 = 16 waves. Wave w owns k0=2w,
// k1=2w+1. MFMA: A=wq[k][o][i] (rows o), B=x[b][i] (cols b) -> D rows
// o=(r&3)+8*(r>>2)+4*h5, col b=l5 (verified). x staged once into LDS
// (bf16). PASS>=1: orp built from vpart4 (float4 chunk sums -> in-register
// squash; round-14/15 verified math). Depth-2 wq prefetch. Per node:
// mfma x2 -> in-reg delta dot + shfl_xor(32) -> delta_lds (x33 pad,
// double-buffered) -> barrier -> thread-remapped softmax -> barrier ->
// accumulate. Epilogue: private partial [k][o][b32] -- NO atomics.
// NOTE: plain launch_bounds; (1024,8) forces spills (round-14: 874MB/pass).
template <int PASS>
__global__ __launch_bounds__(1024) void fused_pass(
    const float* __restrict__ xg,            // fp32 [b][n][i]
    const unsigned short* __restrict__ wq,   // bf16 [n][k][o][i]
    const float* __restrict__ vpart4,        // fp32 [k][o][b][4] chunk sums (PASS>=1)
    float* __restrict__ logits0,             // fp32 [n][b][k]    (PASS>=1)
    float* __restrict__ part)                // fp32 [256 blk][k][o][b32]
{
    __shared__ unsigned short xt_lds[PNB * XT_JS];   // 16896 B
    __shared__ float delta_lds[2][32 * 33];          // 8448 B

    const int tid  = threadIdx.x;
    const int w    = tid >> 6;                   // 0..15
    const int lane = tid & 63;
    const int l5   = lane & 31;                  // b (local) for MFMA cols
    const int h5   = lane >> 5;                  // o-half
    const int set  = blockIdx.x;
    const int hb   = blockIdx.y;
    const int k0   = 2 * w, k1 = 2 * w + 1;
    const int gb5  = hb * 32 + l5;               // global b for this lane
    const int sb   = tid >> 5;                   // softmax-phase local b
    const int sk   = tid & 31;                   // softmax-phase k
    const int nbase = set * PNB;

    // ---- stage x slice -> xt_lds (bf16 [j][b][i], padded rows) ----
#pragma unroll
    for (int rr = 0; rr < 2; ++rr) {
        const int id  = tid + rr * 1024;         // 0..2047
        const int bl  = id >> 6;                 // 0..31 local b
        const int rem = id & 63;
        const int j   = rem >> 2;                // 0..15 node
        const int i4  = rem & 3;
        float4 v = *(const float4*)(xg + ((size_t)(hb * 32 + bl) * NN + (nbase + j)) * NI + i4 * 4);
        ushort4 o4;
        o4.x = f2bf(v.x); o4.y = f2bf(v.y); o4.z = f2bf(v.z); o4.w = f2bf(v.w);
        *(ushort4*)(xt_lds + j * XT_JS + bl * 16 + i4 * 4) = o4;
    }
    __syncthreads();

    // out fragments, packed bf16 pairs (regs r, r+1): squash(sum_c vpart4)
    unsigned orp0[8], orp1[8];
    if constexpr (PASS >= 1) {
        float v0[16], v1[16];
        float sq0 = 0.f, sq1 = 0.f;
#pragma unroll
        for (int r = 0; r < 16; ++r) {
            const int o = (r & 3) + 8 * (r >> 2) + 4 * h5;
            const float4 A = *(const float4*)(vpart4 + (((size_t)k0 * NO + o) * BATCH + gb5) * 4);
            const float4 B = *(const float4*)(vpart4 + (((size_t)k1 * NO + o) * BATCH + gb5) * 4);
            const float a = (A.x + A.y) + (A.z + A.w);
            const float b = (B.x + B.y) + (B.z + B.w);
            v0[r] = a; v1[r] = b;
            sq0 = fmaf(a, a, sq0);
            sq1 = fmaf(b, b, sq1);
        }
        sq0 += __shfl_xor(sq0, 32);              // add other o-half
        sq1 += __shfl_xor(sq1, 32);
        const float cf0 = sq0 / ((1.f + sq0) * sqrtf(sq0));
        const float cf1 = sq1 / ((1.f + sq1) * sqrtf(sq1));
#pragma unroll
        for (int q = 0; q < 8; ++q) {
            orp0[q] = (unsigned)f2bf(v0[2 * q] * cf0) | ((unsigned)f2bf(v0[2 * q + 1] * cf0) << 16);
            orp1[q] = (unsigned)f2bf(v1[2 * q] * cf1) | ((unsigned)f2bf(v1[2 * q + 1] * cf1) << 16);
        }
    }

    float sa0[16], sa1[16];
#pragma unroll
    for (int r = 0; r < 16; ++r) { sa0[r] = 0.f; sa1[r] = 0.f; }

    // depth-2 prefetch of wq fragments (+ logits for PASS 2)
    bf16x8 b0A, b1A, b0B, b1B;
    float gA = 0.f, gB = 0.f;
    {
        const int n = nbase;
        b0A = *(const bf16x8*)(wq + (size_t)n * (NK * NO * NI) + k0 * (NO * NI) + l5 * NI + h5 * 8);
        b1A = *(const bf16x8*)(wq + (size_t)n * (NK * NO * NI) + k1 * (NO * NI) + l5 * NI + h5 * 8);
        b0B = *(const bf16x8*)(wq + (size_t)(n + 1) * (NK * NO * NI) + k0 * (NO * NI) + l5 * NI + h5 * 8);
        b1B = *(const bf16x8*)(wq + (size_t)(n + 1) * (NK * NO * NI) + k1 * (NO * NI) + l5 * NI + h5 * 8);
        if constexpr (PASS == 2) {
            gA = logits0[(size_t)n * (BATCH * NK) + hb * 1024 + tid];
            gB = logits0[(size_t)(n + 1) * (BATCH * NK) + hb * 1024 + tid];
        }
    }

    int buf = 0;
    for (int j = 0; j < PNB; ++j) {
        const int n = nbase + j;
        const bf16x8 b0C = b0A, b1C = b1A;
        const float gC = gA;
        b0A = b0B; b1A = b1B; gA = gB;
        if (j + 2 < PNB) {
            const int n2 = n + 2;
            b0B = *(const bf16x8*)(wq + (size_t)n2 * (NK * NO * NI) + k0 * (NO * NI) + l5 * NI + h5 * 8);
            b1B = *(const bf16x8*)(wq + (size_t)n2 * (NK * NO * NI) + k1 * (NO * NI) + l5 * NI + h5 * 8);
            if constexpr (PASS == 2)
                gB = logits0[(size_t)n2 * (BATCH * NK) + hb * 1024 + tid];
        }
        const bf16x8 aC = *(const bf16x8*)(xt_lds + j * XT_JS + l5 * 16 + h5 * 8);

        f32x16 c0, c1;
#pragma unroll
        for (int r = 0; r < 16; ++r) { c0[r] = 0.f; c1[r] = 0.f; }
        c0 = __builtin_amdgcn_mfma_f32_32x32x16_bf16(b0C, aC, c0, 0, 0, 0);  // A=wq(k0), B=x
        c1 = __builtin_amdgcn_mfma_f32_32x32x16_bf16(b1C, aC, c1, 0, 0, 0);  // A=wq(k1), B=x

        if constexpr (PASS == 0) {
#pragma unroll
            for (int r = 0; r < 16; ++r) { sa0[r] += c0[r]; sa1[r] += c1[r]; }
        } else {
            // in-register delta dot (this lane's o-half), then cross-half sum
            float d0 = 0.f, d1 = 0.f;
#pragma unroll
            for (int r = 0; r < 16; ++r) {
                const unsigned u0 = orp0[r >> 1], u1 = orp1[r >> 1];
                const float o0 = (r & 1) ? bfhi(u0) : bflo(u0);
                const float o1 = (r & 1) ? bfhi(u1) : bflo(u1);
                d0 = fmaf(c0[r], o0, d0);
                d1 = fmaf(c1[r], o1, d1);
            }
            d0 += __shfl_xor(d0, 32);
            d1 += __shfl_xor(d1, 32);

            delta_lds[buf][l5 * 33 + (h5 ? k1 : k0)] = h5 ? d1 : d0;
            __syncthreads();

            // softmax phase: tid -> (sb, sk)
            float l = delta_lds[buf][sb * 33 + sk];
            if constexpr (PASS == 1)
                logits0[(size_t)n * (BATCH * NK) + hb * 1024 + tid] = l;   // coalesced
            else
                l += gC;
            float e = __expf(l);             // no max-subtraction: |l| <= ~8
            float s = e;
#pragma unroll
            for (int mask = 1; mask < 32; mask <<= 1)
                s += __shfl_xor(s, mask);
            delta_lds[buf][sb * 33 + sk] = e / s;    // own slot: no race
            __syncthreads();

            const float p0 = delta_lds[buf][l5 * 33 + k0];
            const float p1 = delta_lds[buf][l5 * 33 + k1];
#pragma unroll
            for (int r = 0; r < 16; ++r) {
                sa0[r] = fmaf(p0, c0[r], sa0[r]);
                sa1[r] = fmaf(p1, c1[r], sa1[r]);
            }
            buf ^= 1;
        }
    }

    // ---- epilogue: coalesced private partial write (NO atomics) ----
    const float scale = (PASS == 0) ? (1.f / NK) : 1.f;
    float* pb = part + ((size_t)(hb * NSETS + set) << 15);     // 32768 floats/blk
#pragma unroll
    for (int r = 0; r < 16; ++r) {
        const int o = (r & 3) + 8 * (r >> 2) + 4 * h5;
        pb[(k0 * NO + o) * 32 + l5] = sa0[r] * scale;
        pb[(k1 * NO + o) * 32 + l5] = sa1[r] * scale;
    }
}

// ---------------- reduce stage-A ----------------
// Grid (32 k, 2 hb, 4 chunks) = 256 blocks x 1024 (full machine). Thread
// (o=t>>5, b=t&31) sums its (k,o,b) over 32 set-partials (coalesced 128B
// line reads), writes the UNsquashed chunk sum to vpart4[k][o][b][c].
__global__ __launch_bounds__(1024) void reduce_stageA(
    const float* __restrict__ part,
    float* __restrict__ vpart4)
{
    const int k  = blockIdx.x;
    const int hb = blockIdx.y;
    const int c  = blockIdx.z;
    const int t  = threadIdx.x;
    const int o  = t >> 5;
    const int b  = t & 31;

    const float* src = part + ((size_t)(hb * NSETS + c * (NSETS / NCH)) << 15)
                            + (k << 10) + (o << 5) + b;
    float v0 = 0.f, v1 = 0.f, v2 = 0.f, v3 = 0.f;
#pragma unroll 4
    for (int s = 0; s < NSETS / NCH; s += 4) {
        v0 += src[(size_t)(s + 0) << 15];
        v1 += src[(size_t)(s + 1) << 15];
        v2 += src[(size_t)(s + 2) << 15];
        v3 += src[(size_t)(s + 3) << 15];
    }
    vpart4[((((size_t)k * NO + o) * BATCH) + hb * 32 + b) * NCH + c] = (v0 + v1) + (v2 + v3);
}

// ---------------- final: sum chunks + squash -> outp ----------------
// Grid (32 k, 2 hb) = 64 blocks x 1024; reads only 1MiB -- trivial.
__global__ __launch_bounds__(1024) void reduce_final(
    const float* __restrict__ vpart4,
    float* __restrict__ outp)
{
    __shared__ float s_lds[32 * 33];
    __shared__ float cf_lds[32];
    const int k  = blockIdx.x;
    const int hb = blockIdx.y;
    const int t  = threadIdx.x;
    const int o  = t >> 5;
    const int b  = t & 31;

    const float4 V = *(const float4*)(vpart4 + (((size_t)k * NO + o) * BATCH + hb * 32 + b) * 4);
    const float v = (V.x + V.y) + (V.z + V.w);
    s_lds[o * 33 + b] = v;
    __syncthreads();
    if (t < 32) {
        float sq = 0.f;
#pragma unroll
        for (int oo = 0; oo < 32; ++oo) { const float x = s_lds[oo * 33 + t]; sq = fmaf(x, x, sq); }
        cf_lds[t] = sq / ((1.f + sq) * sqrtf(sq));
    }
    __syncthreads();
    const int bq = t >> 5, oq = t & 31;              // remap for coalesced out
    outp[(size_t)(hb * 32 + bq) * 1024 + k * 32 + oq] = s_lds[oq * 33 + bq] * cf_lds[bq];
}

// ---------------- legacy fallback (round-2 code, known-good 582 us) ----------------

#define LBB 32
#define LNCHUNK 8
#define LNBLK (NN / LNCHUNK)
#define LTHREADS 512
#define WK_STRIDE 516

template <int PASS>
__global__ __launch_bounds__(LTHREADS, 1) void legacy_pass(
    const float* __restrict__ xg, const float* __restrict__ Wg,
    const float* __restrict__ outvL, float* __restrict__ logits,
    float* __restrict__ partial)
{
    __shared__ float w_lds[NK * WK_STRIDE];
    __shared__ float x_lds[LBB][NI + 1];
    __shared__ float delta_lds[LBB][NK + 1];
    const int t = threadIdx.x, nb = blockIdx.x, bg = blockIdx.y;
    const int b0 = bg * LBB;
    const int k = t >> 4, bq = t & 15, bl0 = bq * 2, bl1 = bq * 2 + 1;
    float acc0[NO], acc1[NO];
#pragma unroll
    for (int o = 0; o < NO; ++o) { acc0[o] = 0.f; acc1[o] = 0.f; }
    float outr0[NO], outr1[NO];
    if constexpr (PASS >= 1) {
        const float4* o0 = (const float4*)&outvL[((b0 + bl0) * NK + k) * NO];
        const float4* o1 = (const float4*)&outvL[((b0 + bl1) * NK + k) * NO];
#pragma unroll
        for (int q = 0; q < NO / 4; ++q) {
            float4 a = o0[q]; float4 b = o1[q];
            outr0[4*q+0]=a.x; outr0[4*q+1]=a.y; outr0[4*q+2]=a.z; outr0[4*q+3]=a.w;
            outr1[4*q+0]=b.x; outr1[4*q+1]=b.y; outr1[4*q+2]=b.z; outr1[4*q+3]=b.w;
        }
    }
    for (int j = 0; j < LNCHUNK; ++j) {
        const int n = nb * LNCHUNK + j;
        __syncthreads();
        {
            const float4* src = (const float4*)(Wg + (size_t)n * (NK * NI * NO));
#pragma unroll
            for (int r = 0; r < (NK * NI * NO / 4) / LTHREADS; ++r) {
                int idx4 = t + r * LTHREADS;
                float4 v = src[idx4];
                int e = idx4 * 4, kk = e >> 9, rem = e & 511;
                *(float4*)&w_lds[kk * WK_STRIDE + rem] = v;
            }
        }
        { int bl = t >> 4, i = t & 15;
          x_lds[bl][i] = xg[((size_t)(b0 + bl) * NN + n) * NI + i]; }
        __syncthreads();
        if constexpr (PASS == 0) {
#pragma unroll
            for (int i = 0; i < NI; ++i) {
                float xa = x_lds[bl0][i], xb = x_lds[bl1][i];
                const float* wrow = &w_lds[k * WK_STRIDE + i * NO];
#pragma unroll
                for (int o = 0; o < NO; ++o) {
                    float w = wrow[o];
                    acc0[o] = fmaf(xa, w, acc0[o]);
                    acc1[o] = fmaf(xb, w, acc1[o]);
                }
            }
        } else {
            float pr0[NO], pr1[NO];
#pragma unroll
            for (int o = 0; o < NO; ++o) { pr0[o] = 0.f; pr1[o] = 0.f; }
#pragma unroll
            for (int i = 0; i < NI; ++i) {
                float xa = x_lds[bl0][i], xb = x_lds[bl1][i];
                const float* wrow = &w_lds[k * WK_STRIDE + i * NO];
#pragma unroll
                for (int o = 0; o < NO; ++o) {
                    float w = wrow[o];
                    pr0[o] = fmaf(xa, w, pr0[o]);
                    pr1[o] = fmaf(xb, w, pr1[o]);
                }
            }
            float d0 = 0.f, d1 = 0.f;
#pragma unroll
            for (int o = 0; o < NO; ++o) {
                d0 = fmaf(pr0[o], outr0[o], d0);
                d1 = fmaf(pr1[o], outr1[o], d1);
            }
            float l0 = d0, l1 = d1;
            const size_t li0 = ((size_t)(b0 + bl0) * NN + n) * NK + k;
            const size_t li1 = ((size_t)(b0 + bl1) * NN + n) * NK + k;
            if constexpr (PASS == 2) { l0 += logits[li0]; l1 += logits[li1]; }
            else { logits[li0] = d0; logits[li1] = d1; }
            delta_lds[bl0][k] = l0; delta_lds[bl1][k] = l1;
            __syncthreads();
            float m0 = -1e30f, m1 = -1e30f;
#pragma unroll
            for (int kk = 0; kk < NK; ++kk) {
                m0 = fmaxf(m0, delta_lds[bl0][kk]);
                m1 = fmaxf(m1, delta_lds[bl1][kk]);
            }
            float s0 = 0.f, s1 = 0.f;
#pragma unroll
            for (int kk = 0; kk < NK; ++kk) {
                s0 += __expf(delta_lds[bl0][kk] - m0);
                s1 += __expf(delta_lds[bl1][kk] - m1);
            }
            float p0 = __expf(l0 - m0) / s0;
            float p1 = __expf(l1 - m1) / s1;
#pragma unroll
            for (int o = 0; o < NO; ++o) {
                acc0[o] = fmaf(p0, pr0[o], acc0[o]);
                acc1[o] = fmaf(p1, pr1[o], acc1[o]);
            }
        }
    }
    const float scale = (PASS == 0) ? (1.f / NK) : 1.f;
    float4* p0 = (float4*)&partial[(((size_t)nb * BATCH + (b0 + bl0)) * NK + k) * NO];
    float4* p1 = (float4*)&partial[(((size_t)nb * BATCH + (b0 + bl1)) * NK + k) * NO];
#pragma unroll
    for (int q = 0; q < NO / 4; ++q) {
        float4 v0, v1;
        v0.x = acc0[4*q+0]*scale; v0.y = acc0[4*q+1]*scale;
        v0.z = acc0[4*q+2]*scale; v0.w = acc0[4*q+3]*scale;
        v1.x = acc1[4*q+0]*scale; v1.y = acc1[4*q+1]*scale;
        v1.z = acc1[4*q+2]*scale; v1.w = acc1[4*q+3]*scale;
        p0[q] = v0; p1[q] = v1;
    }
}

__global__ __launch_bounds__(256) void legacy_reduce(
    const float* __restrict__ partial, float* __restrict__ outf)
{
    const int tid = blockIdx.x * 256 + threadIdx.x;
    float v = 0.f;
    for (int nb = 0; nb < LNBLK; ++nb)
        v += partial[(size_t)nb * (BATCH * NK * NO) + tid];
    float sq = v * v;
#pragma unroll
    for (int off = 1; off < 32; off <<= 1) sq += __shfl_xor(sq, off);
    float coef = sq / ((1.f + sq) * sqrtf(sq));
    outf[tid] = v * coef;
}

// ---------------- launch ----------------

extern "C" void kernel_launch(void* const* d_in, const int* in_sizes, int n_in,
                              void* d_out, int out_size, void* d_ws, size_t ws_size,
                              hipStream_t stream)
{
    const float* xg = (const float*)d_in[0];
    const float* Wg = (const float*)d_in[1];
    float* outp = (float*)d_out;
    char* ws = (char*)d_ws;

    const size_t SZ_WQ     = (size_t)NN * NK * NO * NI * 2;          //  64 MiB
    const size_t SZ_PART   = (size_t)256 * 32768 * 4;                //  32 MiB
    const size_t SZ_LOGITS = (size_t)NN * BATCH * NK * 4;            //  16 MiB
    const size_t SZ_VPART  = (size_t)NK * NO * BATCH * NCH * 4;      //   1 MiB
    const size_t NEED = SZ_WQ + SZ_PART + SZ_LOGITS + SZ_VPART;

    if (ws_size >= NEED) {
        unsigned short* wq = (unsigned short*)ws;
        float* part    = (float*)(ws + SZ_WQ);
        float* logits0 = (float*)(ws + SZ_WQ + SZ_PART);
        float* vpart4  = (float*)(ws + SZ_WQ + SZ_PART + SZ_LOGITS);

        wqt_kernel<<<16384, 256, 0, stream>>>(Wg, wq);

        dim3 pg(NSETS, 2);
        dim3 ra(NK, 2, NCH);
        dim3 fg(NK, 2);
        fused_pass<0><<<pg, 1024, 0, stream>>>(xg, wq, nullptr, nullptr, part);
        reduce_stageA<<<ra, 1024, 0, stream>>>(part, vpart4);
        fused_pass<1><<<pg, 1024, 0, stream>>>(xg, wq, vpart4, logits0, part);
        reduce_stageA<<<ra, 1024, 0, stream>>>(part, vpart4);
        fused_pass<2><<<pg, 1024, 0, stream>>>(xg, wq, vpart4, logits0, part);
        reduce_stageA<<<ra, 1024, 0, stream>>>(part, vpart4);
        reduce_final<<<fg, 1024, 0, stream>>>(vpart4, outp);
    } else {
        float* partial = (float*)ws;
        float* logits = (float*)(ws + (size_t)LNBLK * BATCH * NK * NO * 4);
        float* outvL = (float*)(ws + (size_t)LNBLK * BATCH * NK * NO * 4 + (size_t)BATCH * NN * NK * 4);
        dim3 grid(LNBLK, BATCH / LBB);
        const int rblocks = BATCH * NK * NO / 256;
        legacy_pass<0><<<grid, LTHREADS, 0, stream>>>(xg, Wg, nullptr, logits, partial);
        legacy_reduce<<<rblocks, 256, 0, stream>>>(partial, outvL);
        legacy_pass<1><<<grid, LTHREADS, 0, stream>>>(xg, Wg, outvL, logits, partial);
        legacy_reduce<<<rblocks, 256, 0, stream>>>(partial, outvL);
        legacy_pass<2><<<grid, LTHREADS, 0, stream>>>(xg, Wg, outvL, logits, partial);
        legacy_reduce<<<rblocks, 256, 0, stream>>>(partial, outp);
    }
}

// Round 8
// 321.643 us; speedup vs baseline: 1.1657x; 1.1657x over previous
//
#include <hip/hip_runtime.h>
#include <math.h>

// CapsuleLayer routing on MI355X (gfx950). fp32 in/out.
// B=64, n=2048, k=32, in_C=16, out_C=32, 3 routing iterations.
//
// Round-18: BISECT round-17's regression (336->375 with two bundled
// changes). This round = exact round-13/16 code (334us best-known:
// PNB=16, depth-1 prefetch, grid (NSETS,2)) + ONLY the reduce split:
//  - reduce_stageA (NK,2,4)=256 blocks, each sums 32 set-partials,
//    coalesced write to vpart[c][k][o][b] (1MiB). The old 64-block
//    reduce was CU-count-bound (512KB/block at ~25GB/s per-CU stream
//    cap = 21us); 256 blocks -> ~6us.
//  - orp build in passes 1/2 sums the 4 chunks in-register + squash
//    (round-15 verified math).
//  - tiny reduce_final for the output.
// Depth-2 wq prefetch DROPPED (prime regression suspect: +reg pressure,
// and GEMM lore says source-level prefetch tweaks are neutral-negative).
// If this lands ~370 again, the split is the culprit -> full revert next.

#define BATCH 64
#define NN    2048
#define NK    32
#define NI    16
#define NO    32

#define PNB   16                  // nodes per fused block
#define NSETS (NN / PNB)          // 128 node-sets
#define NCH   4                   // reduce stage-A chunks
#define XT_JS 528                 // ushorts per node-row in xt_lds (32*16 + 16 pad)

typedef __bf16 bf16x8 __attribute__((ext_vector_type(8)));
typedef float  f32x16 __attribute__((ext_vector_type(16)));

__device__ __forceinline__ unsigned short f2bf(float f) {
    unsigned int x = __float_as_uint(f);
    unsigned int lsb = (x >> 16) & 1u;
    x += 0x7fffu + lsb;                 // RNE
    return (unsigned short)(x >> 16);
}
__device__ __forceinline__ float bflo(unsigned int u) { return __uint_as_float(u << 16); }
__device__ __forceinline__ float bfhi(unsigned int u) { return __uint_as_float(u & 0xffff0000u); }

// W fp32 [n][k][i][o] -> wq bf16 [n][k][o][i] (A-fragment-ready).
__global__ __launch_bounds__(256) void wqt_kernel(const float* __restrict__ Wg,
                                                  unsigned short* __restrict__ wq) {
    const int w    = threadIdx.x >> 6;
    const int lane = threadIdx.x & 63;
    const int task = blockIdx.x * 4 + w;          // 65536 = n*32 + k
    const int o  = lane & 31;
    const int ih = lane >> 5;                     // i-half
    const float* src = Wg + (size_t)task * (NI * NO);
    unsigned short d[8];
#pragma unroll
    for (int j = 0; j < 8; ++j)
        d[j] = f2bf(src[(ih * 8 + j) * NO + o]);
    *(uint4*)(wq + (size_t)task * (NO * NI) + o * NI + ih * 8) = *(uint4*)d;
}

// ---------------- fused routing pass ----------------
// Grid (128 sets, 2 b-halves), block 1024 = 16 waves. Wave w owns k0=2w,
// k1=2w+1. MFMA: A=wq[k][o][i] (rows o), B=x[b][i] (cols b) -> D rows
// o=(r&3)+8*(r>>2)+4*h5, col b=l5 (verified). x staged once into LDS
// (bf16). PASS>=1: orp built from vpart[c][k][o][b] (4-chunk in-register
// sum + squash; round-15 verified). Depth-1 wq prefetch (round-3 exact).
// Per node: mfma x2 -> in-reg delta dot + shfl_xor(32) -> delta_lds (x33
// pad, double-buffered) -> barrier -> thread-remapped softmax -> barrier
// -> accumulate. Epilogue: private partial [k][o][b32] -- NO atomics.
// NOTE: plain launch_bounds; (1024,8) forces spills (round-14: 874MB/pass).
template <int PASS>
__global__ __launch_bounds__(1024) void fused_pass(
    const float* __restrict__ xg,            // fp32 [b][n][i]
    const unsigned short* __restrict__ wq,   // bf16 [n][k][o][i]
    const float* __restrict__ vpart,         // fp32 [4][k][o][b] chunk sums (PASS>=1)
    float* __restrict__ logits0,             // fp32 [n][b][k]    (PASS>=1)
    float* __restrict__ part)                // fp32 [256 blk][k][o][b32]
{
    __shared__ unsigned short xt_lds[PNB * XT_JS];   // 16896 B
    __shared__ float delta_lds[2][32 * 33];          // 8448 B

    const int tid  = threadIdx.x;
    const int w    = tid >> 6;                   // 0..15
    const int lane = tid & 63;
    const int l5   = lane & 31;                  // b (local) for MFMA cols
    const int h5   = lane >> 5;                  // o-half
    const int set  = blockIdx.x;
    const int hb   = blockIdx.y;
    const int k0   = 2 * w, k1 = 2 * w + 1;
    const int gb5  = hb * 32 + l5;               // global b for this lane
    const int sb   = tid >> 5;                   // softmax-phase local b
    const int sk   = tid & 31;                   // softmax-phase k
    const int nbase = set * PNB;

    // ---- stage x slice -> xt_lds (bf16 [j][b][i], padded rows) ----
#pragma unroll
    for (int rr = 0; rr < 2; ++rr) {
        const int id  = tid + rr * 1024;         // 0..2047
        const int bl  = id >> 6;                 // 0..31 local b
        const int rem = id & 63;
        const int j   = rem >> 2;                // 0..15 node
        const int i4  = rem & 3;
        float4 v = *(const float4*)(xg + ((size_t)(hb * 32 + bl) * NN + (nbase + j)) * NI + i4 * 4);
        ushort4 o4;
        o4.x = f2bf(v.x); o4.y = f2bf(v.y); o4.z = f2bf(v.z); o4.w = f2bf(v.w);
        *(ushort4*)(xt_lds + j * XT_JS + bl * 16 + i4 * 4) = o4;
    }
    __syncthreads();

    // out fragments, packed bf16 pairs (regs r, r+1): squash(sum_c vpart)
    unsigned orp0[8], orp1[8];
    if constexpr (PASS >= 1) {
        float v0[16], v1[16];
        float sq0 = 0.f, sq1 = 0.f;
#pragma unroll
        for (int r = 0; r < 16; ++r) {
            const int o = (r & 3) + 8 * (r >> 2) + 4 * h5;
            float a = 0.f, b = 0.f;
#pragma unroll
            for (int c = 0; c < NCH; ++c) {
                a += vpart[(((size_t)c * NK + k0) * NO + o) * BATCH + gb5];
                b += vpart[(((size_t)c * NK + k1) * NO + o) * BATCH + gb5];
            }
            v0[r] = a; v1[r] = b;
            sq0 = fmaf(a, a, sq0);
            sq1 = fmaf(b, b, sq1);
        }
        sq0 += __shfl_xor(sq0, 32);              // add other o-half
        sq1 += __shfl_xor(sq1, 32);
        const float cf0 = sq0 / ((1.f + sq0) * sqrtf(sq0));
        const float cf1 = sq1 / ((1.f + sq1) * sqrtf(sq1));
#pragma unroll
        for (int q = 0; q < 8; ++q) {
            orp0[q] = (unsigned)f2bf(v0[2 * q] * cf0) | ((unsigned)f2bf(v0[2 * q + 1] * cf0) << 16);
            orp1[q] = (unsigned)f2bf(v1[2 * q] * cf1) | ((unsigned)f2bf(v1[2 * q + 1] * cf1) << 16);
        }
    }

    float sa0[16], sa1[16];
#pragma unroll
    for (int r = 0; r < 16; ++r) { sa0[r] = 0.f; sa1[r] = 0.f; }

    // depth-1 prefetch of wq fragments (+ logits for PASS 2)
    bf16x8 b0N, b1N;
    float gN = 0.f;
    {
        const int n = nbase;
        b0N = *(const bf16x8*)(wq + (size_t)n * (NK * NO * NI) + k0 * (NO * NI) + l5 * NI + h5 * 8);
        b1N = *(const bf16x8*)(wq + (size_t)n * (NK * NO * NI) + k1 * (NO * NI) + l5 * NI + h5 * 8);
        if constexpr (PASS == 2)
            gN = logits0[(size_t)n * (BATCH * NK) + hb * 1024 + tid];
    }

    int buf = 0;
    for (int j = 0; j < PNB; ++j) {
        const int n = nbase + j;
        const bf16x8 b0C = b0N, b1C = b1N;
        const float gC = gN;
        if (j < PNB - 1) {
            const int n2 = n + 1;
            b0N = *(const bf16x8*)(wq + (size_t)n2 * (NK * NO * NI) + k0 * (NO * NI) + l5 * NI + h5 * 8);
            b1N = *(const bf16x8*)(wq + (size_t)n2 * (NK * NO * NI) + k1 * (NO * NI) + l5 * NI + h5 * 8);
            if constexpr (PASS == 2)
                gN = logits0[(size_t)n2 * (BATCH * NK) + hb * 1024 + tid];
        }
        const bf16x8 aC = *(const bf16x8*)(xt_lds + j * XT_JS + l5 * 16 + h5 * 8);

        f32x16 c0, c1;
#pragma unroll
        for (int r = 0; r < 16; ++r) { c0[r] = 0.f; c1[r] = 0.f; }
        c0 = __builtin_amdgcn_mfma_f32_32x32x16_bf16(b0C, aC, c0, 0, 0, 0);  // A=wq(k0), B=x
        c1 = __builtin_amdgcn_mfma_f32_32x32x16_bf16(b1C, aC, c1, 0, 0, 0);  // A=wq(k1), B=x

        if constexpr (PASS == 0) {
#pragma unroll
            for (int r = 0; r < 16; ++r) { sa0[r] += c0[r]; sa1[r] += c1[r]; }
        } else {
            // in-register delta dot (this lane's o-half), then cross-half sum
            float d0 = 0.f, d1 = 0.f;
#pragma unroll
            for (int r = 0; r < 16; ++r) {
                const unsigned u0 = orp0[r >> 1], u1 = orp1[r >> 1];
                const float o0 = (r & 1) ? bfhi(u0) : bflo(u0);
                const float o1 = (r & 1) ? bfhi(u1) : bflo(u1);
                d0 = fmaf(c0[r], o0, d0);
                d1 = fmaf(c1[r], o1, d1);
            }
            d0 += __shfl_xor(d0, 32);
            d1 += __shfl_xor(d1, 32);

            delta_lds[buf][l5 * 33 + (h5 ? k1 : k0)] = h5 ? d1 : d0;
            __syncthreads();

            // softmax phase: tid -> (sb, sk)
            float l = delta_lds[buf][sb * 33 + sk];
            if constexpr (PASS == 1)
                logits0[(size_t)n * (BATCH * NK) + hb * 1024 + tid] = l;   // coalesced
            else
                l += gC;
            float e = __expf(l);             // no max-subtraction: |l| <= ~8
            float s = e;
#pragma unroll
            for (int mask = 1; mask < 32; mask <<= 1)
                s += __shfl_xor(s, mask);
            delta_lds[buf][sb * 33 + sk] = e / s;    // own slot: no race
            __syncthreads();

            const float p0 = delta_lds[buf][l5 * 33 + k0];
            const float p1 = delta_lds[buf][l5 * 33 + k1];
#pragma unroll
            for (int r = 0; r < 16; ++r) {
                sa0[r] = fmaf(p0, c0[r], sa0[r]);
                sa1[r] = fmaf(p1, c1[r], sa1[r]);
            }
            buf ^= 1;
        }
    }

    // ---- epilogue: coalesced private partial write (NO atomics) ----
    const float scale = (PASS == 0) ? (1.f / NK) : 1.f;
    float* pb = part + ((size_t)(hb * NSETS + set) << 15);     // 32768 floats/blk
#pragma unroll
    for (int r = 0; r < 16; ++r) {
        const int o = (r & 3) + 8 * (r >> 2) + 4 * h5;
        pb[(k0 * NO + o) * 32 + l5] = sa0[r] * scale;
        pb[(k1 * NO + o) * 32 + l5] = sa1[r] * scale;
    }
}

// ---------------- reduce stage-A ----------------
// Grid (32 k, 2 hb, 4 chunks) = 256 blocks x 1024 (full machine). Thread
// (o=t>>5, b=t&31) sums its (k,o,b) over 32 set-partials (coalesced 128B
// line reads), writes the UNsquashed chunk sum to vpart[c][k][o][b]
// (coalesced: b consecutive).
__global__ __launch_bounds__(1024) void reduce_stageA(
    const float* __restrict__ part,
    float* __restrict__ vpart)
{
    const int k  = blockIdx.x;
    const int hb = blockIdx.y;
    const int c  = blockIdx.z;
    const int t  = threadIdx.x;
    const int o  = t >> 5;
    const int b  = t & 31;

    const float* src = part + ((size_t)(hb * NSETS + c * (NSETS / NCH)) << 15)
                            + (k << 10) + (o << 5) + b;
    float v0 = 0.f, v1 = 0.f, v2 = 0.f, v3 = 0.f;
#pragma unroll 4
    for (int s = 0; s < NSETS / NCH; s += 4) {
        v0 += src[(size_t)(s + 0) << 15];
        v1 += src[(size_t)(s + 1) << 15];
        v2 += src[(size_t)(s + 2) << 15];
        v3 += src[(size_t)(s + 3) << 15];
    }
    vpart[(((size_t)c * NK + k) * NO + o) * BATCH + hb * 32 + b] = (v0 + v1) + (v2 + v3);
}

// ---------------- final: sum chunks + squash -> outp ----------------
// Grid (32 k, 2 hb) = 64 blocks x 1024; reads only 1MiB -- trivial.
__global__ __launch_bounds__(1024) void reduce_final(
    const float* __restrict__ vpart,
    float* __restrict__ outp)
{
    __shared__ float s_lds[32 * 33];
    __shared__ float cf_lds[32];
    const int k  = blockIdx.x;
    const int hb = blockIdx.y;
    const int t  = threadIdx.x;
    const int o  = t >> 5;
    const int b  = t & 31;

    float v = 0.f;
#pragma unroll
    for (int c = 0; c < NCH; ++c)
        v += vpart[(((size_t)c * NK + k) * NO + o) * BATCH + hb * 32 + b];
    s_lds[o * 33 + b] = v;
    __syncthreads();
    if (t < 32) {
        float sq = 0.f;
#pragma unroll
        for (int oo = 0; oo < 32; ++oo) { const float x = s_lds[oo * 33 + t]; sq = fmaf(x, x, sq); }
        cf_lds[t] = sq / ((1.f + sq) * sqrtf(sq));
    }
    __syncthreads();
    const int bq = t >> 5, oq = t & 31;              // remap for coalesced out
    outp[(size_t)(hb * 32 + bq) * 1024 + k * 32 + oq] = s_lds[oq * 33 + bq] * cf_lds[bq];
}

// ---------------- legacy fallback (round-2 code, known-good 582 us) ----------------

#define LBB 32
#define LNCHUNK 8
#define LNBLK (NN / LNCHUNK)
#define LTHREADS 512
#define WK_STRIDE 516

template <int PASS>
__global__ __launch_bounds__(LTHREADS, 1) void legacy_pass(
    const float* __restrict__ xg, const float* __restrict__ Wg,
    const float* __restrict__ outvL, float* __restrict__ logits,
    float* __restrict__ partial)
{
    __shared__ float w_lds[NK * WK_STRIDE];
    __shared__ float x_lds[LBB][NI + 1];
    __shared__ float delta_lds[LBB][NK + 1];
    const int t = threadIdx.x, nb = blockIdx.x, bg = blockIdx.y;
    const int b0 = bg * LBB;
    const int k = t >> 4, bq = t & 15, bl0 = bq * 2, bl1 = bq * 2 + 1;
    float acc0[NO], acc1[NO];
#pragma unroll
    for (int o = 0; o < NO; ++o) { acc0[o] = 0.f; acc1[o] = 0.f; }
    float outr0[NO], outr1[NO];
    if constexpr (PASS >= 1) {
        const float4* o0 = (const float4*)&outvL[((b0 + bl0) * NK + k) * NO];
        const float4* o1 = (const float4*)&outvL[((b0 + bl1) * NK + k) * NO];
#pragma unroll
        for (int q = 0; q < NO / 4; ++q) {
            float4 a = o0[q]; float4 b = o1[q];
            outr0[4*q+0]=a.x; outr0[4*q+1]=a.y; outr0[4*q+2]=a.z; outr0[4*q+3]=a.w;
            outr1[4*q+0]=b.x; outr1[4*q+1]=b.y; outr1[4*q+2]=b.z; outr1[4*q+3]=b.w;
        }
    }
    for (int j = 0; j < LNCHUNK; ++j) {
        const int n = nb * LNCHUNK + j;
        __syncthreads();
        {
            const float4* src = (const float4*)(Wg + (size_t)n * (NK * NI * NO));
#pragma unroll
            for (int r = 0; r < (NK * NI * NO / 4) / LTHREADS; ++r) {
                int idx4 = t + r * LTHREADS;
                float4 v = src[idx4];
                int e = idx4 * 4, kk = e >> 9, rem = e & 511;
                *(float4*)&w_lds[kk * WK_STRIDE + rem] = v;
            }
        }
        { int bl = t >> 4, i = t & 15;
          x_lds[bl][i] = xg[((size_t)(b0 + bl) * NN + n) * NI + i]; }
        __syncthreads();
        if constexpr (PASS == 0) {
#pragma unroll
            for (int i = 0; i < NI; ++i) {
                float xa = x_lds[bl0][i], xb = x_lds[bl1][i];
                const float* wrow = &w_lds[k * WK_STRIDE + i * NO];
#pragma unroll
                for (int o = 0; o < NO; ++o) {
                    float w = wrow[o];
                    acc0[o] = fmaf(xa, w, acc0[o]);
                    acc1[o] = fmaf(xb, w, acc1[o]);
                }
            }
        } else {
            float pr0[NO], pr1[NO];
#pragma unroll
            for (int o = 0; o < NO; ++o) { pr0[o] = 0.f; pr1[o] = 0.f; }
#pragma unroll
            for (int i = 0; i < NI; ++i) {
                float xa = x_lds[bl0][i], xb = x_lds[bl1][i];
                const float* wrow = &w_lds[k * WK_STRIDE + i * NO];
#pragma unroll
                for (int o = 0; o < NO; ++o) {
                    float w = wrow[o];
                    pr0[o] = fmaf(xa, w, pr0[o]);
                    pr1[o] = fmaf(xb, w, pr1[o]);
                }
            }
            float d0 = 0.f, d1 = 0.f;
#pragma unroll
            for (int o = 0; o < NO; ++o) {
                d0 = fmaf(pr0[o], outr0[o], d0);
                d1 = fmaf(pr1[o], outr1[o], d1);
            }
            float l0 = d0, l1 = d1;
            const size_t li0 = ((size_t)(b0 + bl0) * NN + n) * NK + k;
            const size_t li1 = ((size_t)(b0 + bl1) * NN + n) * NK + k;
            if constexpr (PASS == 2) { l0 += logits[li0]; l1 += logits[li1]; }
            else { logits[li0] = d0; logits[li1] = d1; }
            delta_lds[bl0][k] = l0; delta_lds[bl1][k] = l1;
            __syncthreads();
            float m0 = -1e30f, m1 = -1e30f;
#pragma unroll
            for (int kk = 0; kk < NK; ++kk) {
                m0 = fmaxf(m0, delta_lds[bl0][kk]);
                m1 = fmaxf(m1, delta_lds[bl1][kk]);
            }
            float s0 = 0.f, s1 = 0.f;
#pragma unroll
            for (int kk = 0; kk < NK; ++kk) {
                s0 += __expf(delta_lds[bl0][kk] - m0);
                s1 += __expf(delta_lds[bl1][kk] - m1);
            }
            float p0 = __expf(l0 - m0) / s0;
            float p1 = __expf(l1 - m1) / s1;
#pragma unroll
            for (int o = 0; o < NO; ++o) {
                acc0[o] = fmaf(p0, pr0[o], acc0[o]);
                acc1[o] = fmaf(p1, pr1[o], acc1[o]);
            }
        }
    }
    const float scale = (PASS == 0) ? (1.f / NK) : 1.f;
    float4* p0 = (float4*)&partial[(((size_t)nb * BATCH + (b0 + bl0)) * NK + k) * NO];
    float4* p1 = (float4*)&partial[(((size_t)nb * BATCH + (b0 + bl1)) * NK + k) * NO];
#pragma unroll
    for (int q = 0; q < NO / 4; ++q) {
        float4 v0, v1;
        v0.x = acc0[4*q+0]*scale; v0.y = acc0[4*q+1]*scale;
        v0.z = acc0[4*q+2]*scale; v0.w = acc0[4*q+3]*scale;
        v1.x = acc1[4*q+0]*scale; v1.y = acc1[4*q+1]*scale;
        v1.z = acc1[4*q+2]*scale; v1.w = acc1[4*q+3]*scale;
        p0[q] = v0; p1[q] = v1;
    }
}

__global__ __launch_bounds__(256) void legacy_reduce(
    const float* __restrict__ partial, float* __restrict__ outf)
{
    const int tid = blockIdx.x * 256 + threadIdx.x;
    float v = 0.f;
    for (int nb = 0; nb < LNBLK; ++nb)
        v += partial[(size_t)nb * (BATCH * NK * NO) + tid];
    float sq = v * v;
#pragma unroll
    for (int off = 1; off < 32; off <<= 1) sq += __shfl_xor(sq, off);
    float coef = sq / ((1.f + sq) * sqrtf(sq));
    outf[tid] = v * coef;
}

// ---------------- launch ----------------

extern "C" void kernel_launch(void* const* d_in, const int* in_sizes, int n_in,
                              void* d_out, int out_size, void* d_ws, size_t ws_size,
                              hipStream_t stream)
{
    const float* xg = (const float*)d_in[0];
    const float* Wg = (const float*)d_in[1];
    float* outp = (float*)d_out;
    char* ws = (char*)d_ws;

    const size_t SZ_WQ     = (size_t)NN * NK * NO * NI * 2;          //  64 MiB
    const size_t SZ_PART   = (size_t)256 * 32768 * 4;                //  32 MiB
    const size_t SZ_LOGITS = (size_t)NN * BATCH * NK * 4;            //  16 MiB
    const size_t SZ_VPART  = (size_t)NCH * NK * NO * BATCH * 4;      //   1 MiB
    const size_t NEED = SZ_WQ + SZ_PART + SZ_LOGITS + SZ_VPART;

    if (ws_size >= NEED) {
        unsigned short* wq = (unsigned short*)ws;
        float* part    = (float*)(ws + SZ_WQ);
        float* logits0 = (float*)(ws + SZ_WQ + SZ_PART);
        float* vpart   = (float*)(ws + SZ_WQ + SZ_PART + SZ_LOGITS);

        wqt_kernel<<<16384, 256, 0, stream>>>(Wg, wq);

        dim3 pg(NSETS, 2);
        dim3 ra(NK, 2, NCH);
        dim3 fg(NK, 2);
        fused_pass<0><<<pg, 1024, 0, stream>>>(xg, wq, nullptr, nullptr, part);
        reduce_stageA<<<ra, 1024, 0, stream>>>(part, vpart);
        fused_pass<1><<<pg, 1024, 0, stream>>>(xg, wq, vpart, logits0, part);
        reduce_stageA<<<ra, 1024, 0, stream>>>(part, vpart);
        fused_pass<2><<<pg, 1024, 0, stream>>>(xg, wq, vpart, logits0, part);
        reduce_stageA<<<ra, 1024, 0, stream>>>(part, vpart);
        reduce_final<<<fg, 1024, 0, stream>>>(vpart, outp);
    } else {
        float* partial = (float*)ws;
        float* logits = (float*)(ws + (size_t)LNBLK * BATCH * NK * NO * 4);
        float* outvL = (float*)(ws + (size_t)LNBLK * BATCH * NK * NO * 4 + (size_t)BATCH * NN * NK * 4);
        dim3 grid(LNBLK, BATCH / LBB);
        const int rblocks = BATCH * NK * NO / 256;
        legacy_pass<0><<<grid, LTHREADS, 0, stream>>>(xg, Wg, nullptr, logits, partial);
        legacy_reduce<<<rblocks, 256, 0, stream>>>(partial, outvL);
        legacy_pass<1><<<grid, LTHREADS, 0, stream>>>(xg, Wg, outvL, logits, partial);
        legacy_reduce<<<rblocks, 256, 0, stream>>>(partial, outvL);
        legacy_pass<2><<<grid, LTHREADS, 0, stream>>>(xg, Wg, outvL, logits, partial);
        legacy_reduce<<<rblocks, 256, 0, stream>>>(partial, outp);
    }
}